// Round 1
// baseline (882.398 us; speedup 1.0000x reference)
//
#include <hip/hip_runtime.h>
#include <math.h>

// ---------------------------------------------------------------------------
// Algebraic reductions applied (verified against the reference):
//  * 2-step message-passing loop is idempotent -> run once.
//  * Node branch (x_node, nt_*, ngru_*, natt_b) cancels in softmax -> skipped.
//  * Node attn weights: w[b,i,j] = softmax_j( eh[b,i,j] . natt_w[128:256] ).
//  * Edge attn: w2_row = sigmoid((u_j - u_i)), u = nh_p . eatt_w[0:128].
//  * (e01 + e10)/2 == e01 = s*nh_p[i1] + (1-s)*nh_p[i0], s = sigmoid(u1-u0).
// Input indices:
//  1: x_edge [16,64,64,512]   6: et_w [512,128]   7: et_b [128]
// 11: egru_wih [384,128]     12: egru_bih [384]  13: egru_bhh [384]
// 14: natt_w [256]           16: eatt_w [256]
// 18..29: lr/cr/mr w1[256,512] b1[512] w2[512,od] b2[od], od = 6/5/3
// 30: object_pairs [16,128,2] int32
// Output: [16,128,14] f32
// ---------------------------------------------------------------------------

#define DEVINL __device__ __forceinline__

DEVINL float sigmoidf_(float x) { return 1.0f / (1.0f + __expf(-x)); }
DEVINL float tanhf_(float x) {
    float e = __expf(2.0f * x);
    return (e - 1.0f) / (e + 1.0f);
}

// ---------------- tiled f32 GEMM: C = act(A @ B(+T) + bias) -----------------
// BM=64, BN=64, BK=16, 256 threads, 4x4 per thread. M%64==0, N%64==0, K%16==0.
template <bool BT, bool RELU>
__global__ __launch_bounds__(256) void gemm_f32(
    const float* __restrict__ A, const float* __restrict__ B,
    const float* __restrict__ bias, float* __restrict__ C,
    int M, int N, int K)
{
    __shared__ float As[16][64];
    __shared__ float Bs[16][64];
    const int t  = threadIdx.x;
    const int bm = blockIdx.x * 64;
    const int bn = blockIdx.y * 64;
    const int tr = t >> 4, tc = t & 15;

    float acc[4][4] = {};

    for (int kt = 0; kt < K; kt += 16) {
#pragma unroll
        for (int l = 0; l < 4; ++l) {
            int e = t + l * 256;
            int m = e >> 4, k = e & 15;
            As[k][m] = A[(size_t)(bm + m) * K + kt + k];
        }
#pragma unroll
        for (int l = 0; l < 4; ++l) {
            int e = t + l * 256;
            if (!BT) {
                int k = e >> 6, n = e & 63;
                Bs[k][n] = B[(size_t)(kt + k) * N + bn + n];
            } else {
                int n = e >> 4, k = e & 15;
                Bs[k][n] = B[(size_t)(bn + n) * K + kt + k];
            }
        }
        __syncthreads();
#pragma unroll
        for (int k = 0; k < 16; ++k) {
            const float4 a4 = *(const float4*)(&As[k][tr * 4]);
            const float4 b4 = *(const float4*)(&Bs[k][tc * 4]);
            const float av[4] = {a4.x, a4.y, a4.z, a4.w};
            const float bv[4] = {b4.x, b4.y, b4.z, b4.w};
#pragma unroll
            for (int i = 0; i < 4; ++i)
#pragma unroll
                for (int j = 0; j < 4; ++j)
                    acc[i][j] = fmaf(av[i], bv[j], acc[i][j]);
        }
        __syncthreads();
    }

    const float4 bb = *(const float4*)(&bias[bn + tc * 4]);
    const float bv[4] = {bb.x, bb.y, bb.z, bb.w};
#pragma unroll
    for (int i = 0; i < 4; ++i) {
        int row = bm + tr * 4 + i;
        float4 v;
        float o0 = acc[i][0] + bv[0];
        float o1 = acc[i][1] + bv[1];
        float o2 = acc[i][2] + bv[2];
        float o3 = acc[i][3] + bv[3];
        if (RELU) {
            o0 = fmaxf(o0, 0.f); o1 = fmaxf(o1, 0.f);
            o2 = fmaxf(o2, 0.f); o3 = fmaxf(o3, 0.f);
        }
        v.x = o0; v.y = o1; v.z = o2; v.w = o3;
        *(float4*)(&C[(size_t)row * N + bn + tc * 4]) = v;
    }
}

// ---------------- GRU gates: eh = (1-z)*n --------------------------------
__global__ __launch_bounds__(256) void gru_gates(
    const float* __restrict__ g, const float* __restrict__ bhh,
    float* __restrict__ out, int M)
{
    int idx = blockIdx.x * 256 + threadIdx.x;
    if (idx >= M * 128) return;
    int m = idx >> 7, o = idx & 127;
    const float* gr = g + (size_t)m * 384;
    float xr = gr[o], xz = gr[128 + o], xn = gr[256 + o];
    float r = sigmoidf_(xr + bhh[o]);
    float z = sigmoidf_(xz + bhh[128 + o]);
    float n = tanhf_(xn + r * bhh[256 + o]);
    out[idx] = (1.0f - z) * n;
}

// -------- per-(b,i) attention pooling: nh_p, u -----------------------------
// eh: [G*64, 128] for G groups of this chunk; one block per group, 256 thr.
__global__ __launch_bounds__(256) void pool_kernel(
    const float* __restrict__ eh, const float* __restrict__ natt_w,
    const float* __restrict__ eatt_w, float* __restrict__ nh_p,
    float* __restrict__ u, int group_base)
{
    __shared__ float red[256];
    __shared__ float s2[64];
    __shared__ float ew[64];
    const int t = threadIdx.x;
    const int g = blockIdx.x;
    const float* ebase = eh + (size_t)g * 64 * 128;

    // phase 1: s2[j] = eh[j,:] . natt_w[128:256]
    {
        int j = t >> 2, q = t & 3;
        const float* row = ebase + j * 128 + q * 32;
        const float* wb  = natt_w + 128 + q * 32;
        float acc = 0.f;
#pragma unroll
        for (int k = 0; k < 32; ++k) acc = fmaf(row[k], wb[k], acc);
        red[t] = acc;
    }
    __syncthreads();
    if (t < 64) s2[t] = red[4 * t] + red[4 * t + 1] + red[4 * t + 2] + red[4 * t + 3];
    __syncthreads();

    // phase 2: softmax weights (unnormalized) into ew
    if (t < 64) {
        float m = -1e30f;
        for (int j = 0; j < 64; ++j) m = fmaxf(m, s2[j]);
        ew[t] = __expf(s2[t] - m);
    }
    __syncthreads();
    float inv = 0.f;
    for (int j = 0; j < 64; ++j) inv += ew[j];
    inv = 1.0f / inv;

    // phase 3: nh_p[o] = sum_j w_j * eh[j,o]
    {
        int o = t & 127, h = t >> 7;
        float acc = 0.f;
        for (int j = h * 32; j < h * 32 + 32; ++j)
            acc = fmaf(ew[j], ebase[(size_t)j * 128 + o], acc);
        red[t] = acc;
    }
    __syncthreads();
    if (t < 128) {
        float v = (red[t] + red[t + 128]) * inv;
        nh_p[(size_t)(group_base + g) * 128 + t] = v;
        red[t] = v * eatt_w[t];
    }
    __syncthreads();
    for (int s = 64; s > 0; s >>= 1) {
        if (t < s) red[t] += red[t + s];
        __syncthreads();
    }
    if (t == 0) u[group_base + g] = red[0];
}

// -------- classifier input: ci[b,p,0:128]=mean emb, [128:256]=edge blend ---
__global__ __launch_bounds__(128) void ci_kernel(
    const float* __restrict__ nh_p, const float* __restrict__ u,
    const int* __restrict__ pairs, float* __restrict__ ci)
{
    const int bp = blockIdx.x;          // b*128 + p
    const int b  = bp >> 7;
    const int t  = threadIdx.x;         // 0..127
    int i0 = pairs[bp * 2 + 0];
    int i1 = pairs[bp * 2 + 1];
    const float* n0 = nh_p + (size_t)(b * 64 + i0) * 128;
    const float* n1 = nh_p + (size_t)(b * 64 + i1) * 128;
    float s = sigmoidf_(u[b * 64 + i1] - u[b * 64 + i0]);
    float v0 = n0[t], v1 = n1[t];
    ci[(size_t)bp * 256 + t]        = 0.5f * (v0 + v1);
    ci[(size_t)bp * 256 + 128 + t]  = s * v1 + (1.0f - s) * v0;
}

// -------- 3 fused MLP heads: out[r,14] ------------------------------------
__global__ __launch_bounds__(256) void heads_kernel(
    const float* __restrict__ ci,
    const float* __restrict__ w1a, const float* __restrict__ b1a,
    const float* __restrict__ w2a, const float* __restrict__ b2a,
    const float* __restrict__ w1b, const float* __restrict__ b1b,
    const float* __restrict__ w2b, const float* __restrict__ b2b,
    const float* __restrict__ w1c, const float* __restrict__ b1c,
    const float* __restrict__ w2c, const float* __restrict__ b2c,
    float* __restrict__ out)
{
    __shared__ float cs[8][256];
    __shared__ float hs[8][512];
    const int t  = threadIdx.x;
    const int r0 = blockIdx.x * 8;

#pragma unroll
    for (int l = 0; l < 8; ++l) {
        int e = t + l * 256;
        int r = e >> 8, c = e & 255;
        cs[r][c] = ci[(size_t)(r0 + r) * 256 + c];
    }
    __syncthreads();

    const float* W1[3] = {w1a, w1b, w1c};
    const float* B1[3] = {b1a, b1b, b1c};
    const float* W2[3] = {w2a, w2b, w2c};
    const float* B2[3] = {b2a, b2b, b2c};
    const int OD[3]  = {6, 5, 3};
    const int OFF[3] = {0, 6, 11};

    for (int h = 0; h < 3; ++h) {
        const float* W1h = W1[h];
        const float* b1h = B1[h];
        for (int e = t; e < 8 * 512; e += 256) {
            int r = e >> 9, c = e & 511;
            float acc = b1h[c];
            const float* crow = cs[r];
#pragma unroll 4
            for (int k = 0; k < 256; ++k)
                acc = fmaf(crow[k], W1h[(size_t)k * 512 + c], acc);
            hs[r][c] = fmaxf(acc, 0.f);
        }
        __syncthreads();
        const float* W2h = W2[h];
        const float* b2h = B2[h];
        const int od = OD[h], off = OFF[h];
        for (int e = t; e < 8 * od; e += 256) {
            int r = e / od, o = e - r * od;
            float acc = b2h[o];
            for (int c = 0; c < 512; ++c)
                acc = fmaf(hs[r][c], W2h[c * od + o], acc);
            out[(size_t)(r0 + r) * 14 + off + o] = acc;
        }
        __syncthreads();
    }
}

// ---------------------------------------------------------------------------
extern "C" void kernel_launch(void* const* d_in, const int* in_sizes, int n_in,
                              void* d_out, int out_size, void* d_ws, size_t ws_size,
                              hipStream_t stream)
{
    const float* x_edge   = (const float*)d_in[1];
    const float* et_w     = (const float*)d_in[6];
    const float* et_b     = (const float*)d_in[7];
    const float* egru_wih = (const float*)d_in[11];
    const float* egru_bih = (const float*)d_in[12];
    const float* egru_bhh = (const float*)d_in[13];
    const float* natt_w   = (const float*)d_in[14];
    const float* eatt_w   = (const float*)d_in[16];
    const float* lr_w1 = (const float*)d_in[18];
    const float* lr_b1 = (const float*)d_in[19];
    const float* lr_w2 = (const float*)d_in[20];
    const float* lr_b2 = (const float*)d_in[21];
    const float* cr_w1 = (const float*)d_in[22];
    const float* cr_b1 = (const float*)d_in[23];
    const float* cr_w2 = (const float*)d_in[24];
    const float* cr_b2 = (const float*)d_in[25];
    const float* mr_w1 = (const float*)d_in[26];
    const float* mr_b1 = (const float*)d_in[27];
    const float* mr_w2 = (const float*)d_in[28];
    const float* mr_b2 = (const float*)d_in[29];
    const int* pairs   = (const int*)d_in[30];
    float* out = (float*)d_out;
    float* ws  = (float*)d_ws;

    const int Mtot = 16 * 64 * 64;          // 65536 edge rows

    // fixed workspace: nh_p [1024,128], u [1024], ci [2048,256]
    const size_t NHP_F = 1024 * 128;
    const size_t U_F   = 1024;
    const size_t CI_F  = 2048 * 256;
    const size_t fixed_f = NHP_F + U_F + CI_F;

    int CH = 1;
    while (CH < 64) {
        size_t need = (fixed_f + (size_t)(Mtot / CH) * 512) * sizeof(float);
        if (need <= ws_size) break;
        CH *= 2;
    }
    const int Mc = Mtot / CH;               // edge rows per chunk (mult of 64)
    const int groups_per_chunk = Mc / 64;   // (b,i) groups per chunk

    float* nh_p = ws;
    float* u    = nh_p + NHP_F;
    float* ci   = u + U_F;
    float* g_c  = ci + CI_F;                    // [Mc,384]
    float* ef_c = g_c + (size_t)Mc * 384;       // [Mc,128], reused as eh_c

    for (int c = 0; c < CH; ++c) {
        const float* A = x_edge + (size_t)c * Mc * 512;
        // edge_f = x_edge @ et_w + et_b
        gemm_f32<false, false><<<dim3(Mc / 64, 128 / 64), 256, 0, stream>>>(
            A, et_w, et_b, ef_c, Mc, 128, 512);
        // g = edge_f @ egru_wih^T + egru_bih
        gemm_f32<true, false><<<dim3(Mc / 64, 384 / 64), 256, 0, stream>>>(
            ef_c, egru_wih, egru_bih, g_c, Mc, 384, 128);
        // GRU gates -> eh (overwrite ef_c)
        gru_gates<<<(Mc * 128) / 256, 256, 0, stream>>>(g_c, egru_bhh, ef_c, Mc);
        // softmax-pool over j -> nh_p, u
        pool_kernel<<<groups_per_chunk, 256, 0, stream>>>(
            ef_c, natt_w, eatt_w, nh_p, u, c * groups_per_chunk);
    }

    ci_kernel<<<2048, 128, 0, stream>>>(nh_p, u, pairs, ci);

    heads_kernel<<<2048 / 8, 256, 0, stream>>>(
        ci, lr_w1, lr_b1, lr_w2, lr_b2, cr_w1, cr_b1, cr_w2, cr_b2,
        mr_w1, mr_b1, mr_w2, mr_b2, out);
}

// Round 2
// 396.713 us; speedup vs baseline: 2.2243x; 2.2243x over previous
//
#include <hip/hip_runtime.h>
#include <math.h>

// ---------------------------------------------------------------------------
// Algebraic reductions applied (verified against the reference):
//  * 2-step message-passing loop is idempotent -> run once.
//  * Node branch (x_node, nt_*, ngru_*, natt_b) cancels in softmax -> skipped.
//  * Node attn weights: w[b,i,j] = softmax_j( eh[b,i,j] . natt_w[128:256] ).
//  * Edge attn: w2_row = sigmoid((u_j - u_i)), u = nh_p . eatt_w[0:128].
//  * (e01 + e10)/2 == e01 = s*nh_p[i1] + (1-s)*nh_p[i0], s = sigmoid(u1-u0).
// Input indices:
//  1: x_edge [16,64,64,512]   6: et_w [512,128]   7: et_b [128]
// 11: egru_wih [384,128]     12: egru_bih [384]  13: egru_bhh [384]
// 14: natt_w [256]           16: eatt_w [256]
// 18..29: lr/cr/mr w1[256,512] b1[512] w2[512,od] b2[od], od = 6/5/3
// 30: object_pairs [16,128,2] int32
// Output: [16,128,14] f32
// ---------------------------------------------------------------------------

#define DEVINL __device__ __forceinline__

DEVINL float sigmoidf_(float x) { return 1.0f / (1.0f + __expf(-x)); }
DEVINL float tanhf_(float x) {
    float e = __expf(2.0f * x);
    return (e - 1.0f) / (e + 1.0f);
}

// ---------------- tiled f32 GEMM: C = act(A @ B(+T) + bias) -----------------
// BM=64, BN=64, BK=16, 256 threads, 4x4 per thread. M%64==0, N%64==0, K%16==0.
template <bool BT, bool RELU>
__global__ __launch_bounds__(256) void gemm_f32(
    const float* __restrict__ A, const float* __restrict__ B,
    const float* __restrict__ bias, float* __restrict__ C,
    int M, int N, int K)
{
    __shared__ float As[16][64];
    __shared__ float Bs[16][64];
    const int t  = threadIdx.x;
    const int bm = blockIdx.x * 64;
    const int bn = blockIdx.y * 64;
    const int tr = t >> 4, tc = t & 15;

    float acc[4][4] = {};

    for (int kt = 0; kt < K; kt += 16) {
#pragma unroll
        for (int l = 0; l < 4; ++l) {
            int e = t + l * 256;
            int m = e >> 4, k = e & 15;
            As[k][m] = A[(size_t)(bm + m) * K + kt + k];
        }
#pragma unroll
        for (int l = 0; l < 4; ++l) {
            int e = t + l * 256;
            if (!BT) {
                int k = e >> 6, n = e & 63;
                Bs[k][n] = B[(size_t)(kt + k) * N + bn + n];
            } else {
                int n = e >> 4, k = e & 15;
                Bs[k][n] = B[(size_t)(bn + n) * K + kt + k];
            }
        }
        __syncthreads();
#pragma unroll
        for (int k = 0; k < 16; ++k) {
            const float4 a4 = *(const float4*)(&As[k][tr * 4]);
            const float4 b4 = *(const float4*)(&Bs[k][tc * 4]);
            const float av[4] = {a4.x, a4.y, a4.z, a4.w};
            const float bv[4] = {b4.x, b4.y, b4.z, b4.w};
#pragma unroll
            for (int i = 0; i < 4; ++i)
#pragma unroll
                for (int j = 0; j < 4; ++j)
                    acc[i][j] = fmaf(av[i], bv[j], acc[i][j]);
        }
        __syncthreads();
    }

    const float4 bb = *(const float4*)(&bias[bn + tc * 4]);
    const float bv[4] = {bb.x, bb.y, bb.z, bb.w};
#pragma unroll
    for (int i = 0; i < 4; ++i) {
        int row = bm + tr * 4 + i;
        float4 v;
        float o0 = acc[i][0] + bv[0];
        float o1 = acc[i][1] + bv[1];
        float o2 = acc[i][2] + bv[2];
        float o3 = acc[i][3] + bv[3];
        if (RELU) {
            o0 = fmaxf(o0, 0.f); o1 = fmaxf(o1, 0.f);
            o2 = fmaxf(o2, 0.f); o3 = fmaxf(o3, 0.f);
        }
        v.x = o0; v.y = o1; v.z = o2; v.w = o3;
        *(float4*)(&C[(size_t)row * N + bn + tc * 4]) = v;
    }
}

// ---------------- GRU gates: eh = (1-z)*n --------------------------------
__global__ __launch_bounds__(256) void gru_gates(
    const float* __restrict__ g, const float* __restrict__ bhh,
    float* __restrict__ out, int M)
{
    int idx = blockIdx.x * 256 + threadIdx.x;
    if (idx >= M * 128) return;
    int m = idx >> 7, o = idx & 127;
    const float* gr = g + (size_t)m * 384;
    float xr = gr[o], xz = gr[128 + o], xn = gr[256 + o];
    float r = sigmoidf_(xr + bhh[o]);
    float z = sigmoidf_(xz + bhh[128 + o]);
    float n = tanhf_(xn + r * bhh[256 + o]);
    out[idx] = (1.0f - z) * n;
}

// -------- per-(b,i) attention pooling: nh_p, u -----------------------------
// eh: [G*64, 128] for G groups of this chunk; one block per group, 256 thr.
__global__ __launch_bounds__(256) void pool_kernel(
    const float* __restrict__ eh, const float* __restrict__ natt_w,
    const float* __restrict__ eatt_w, float* __restrict__ nh_p,
    float* __restrict__ u, int group_base)
{
    __shared__ float red[256];
    __shared__ float s2[64];
    __shared__ float ew[64];
    const int t = threadIdx.x;
    const int g = blockIdx.x;
    const float* ebase = eh + (size_t)g * 64 * 128;

    // phase 1: s2[j] = eh[j,:] . natt_w[128:256]
    {
        int j = t >> 2, q = t & 3;
        const float* row = ebase + j * 128 + q * 32;
        const float* wb  = natt_w + 128 + q * 32;
        float acc = 0.f;
#pragma unroll
        for (int k = 0; k < 32; ++k) acc = fmaf(row[k], wb[k], acc);
        red[t] = acc;
    }
    __syncthreads();
    if (t < 64) s2[t] = red[4 * t] + red[4 * t + 1] + red[4 * t + 2] + red[4 * t + 3];
    __syncthreads();

    // phase 2: softmax weights (unnormalized) into ew
    if (t < 64) {
        float m = -1e30f;
        for (int j = 0; j < 64; ++j) m = fmaxf(m, s2[j]);
        ew[t] = __expf(s2[t] - m);
    }
    __syncthreads();
    float inv = 0.f;
    for (int j = 0; j < 64; ++j) inv += ew[j];
    inv = 1.0f / inv;

    // phase 3: nh_p[o] = sum_j w_j * eh[j,o]
    {
        int o = t & 127, h = t >> 7;
        float acc = 0.f;
        for (int j = h * 32; j < h * 32 + 32; ++j)
            acc = fmaf(ew[j], ebase[(size_t)j * 128 + o], acc);
        red[t] = acc;
    }
    __syncthreads();
    if (t < 128) {
        float v = (red[t] + red[t + 128]) * inv;
        nh_p[(size_t)(group_base + g) * 128 + t] = v;
        red[t] = v * eatt_w[t];
    }
    __syncthreads();
    for (int s = 64; s > 0; s >>= 1) {
        if (t < s) red[t] += red[t + s];
        __syncthreads();
    }
    if (t == 0) u[group_base + g] = red[0];
}

// -------- classifier input: ci[b,p,0:128]=mean emb, [128:256]=edge blend ---
__global__ __launch_bounds__(128) void ci_kernel(
    const float* __restrict__ nh_p, const float* __restrict__ u,
    const int* __restrict__ pairs, float* __restrict__ ci)
{
    const int bp = blockIdx.x;          // b*128 + p
    const int b  = bp >> 7;
    const int t  = threadIdx.x;         // 0..127
    int i0 = pairs[bp * 2 + 0];
    int i1 = pairs[bp * 2 + 1];
    const float* n0 = nh_p + (size_t)(b * 64 + i0) * 128;
    const float* n1 = nh_p + (size_t)(b * 64 + i1) * 128;
    float s = sigmoidf_(u[b * 64 + i1] - u[b * 64 + i0]);
    float v0 = n0[t], v1 = n1[t];
    ci[(size_t)bp * 256 + t]        = 0.5f * (v0 + v1);
    ci[(size_t)bp * 256 + 128 + t]  = s * v1 + (1.0f - s) * v0;
}

// -------- head layer 2: one wave per (row, o) ------------------------------
// h: [2048,512]; w2: [512,od]; out[row,14], slice at `off`.
__global__ __launch_bounds__(256) void layer2_kernel(
    const float* __restrict__ h, const float* __restrict__ w2,
    const float* __restrict__ b2, float* __restrict__ out, int od, int off)
{
    const int wv   = threadIdx.x >> 6;
    const int lane = threadIdx.x & 63;
    const int idx  = blockIdx.x * 4 + wv;       // row*od + o
    if (idx >= 2048 * od) return;
    const int row = idx / od;
    const int o   = idx - row * od;
    const float* hr = h + (size_t)row * 512;
    float acc = 0.f;
#pragma unroll
    for (int c = lane; c < 512; c += 64)
        acc = fmaf(hr[c], w2[(size_t)c * od + o], acc);
#pragma unroll
    for (int s = 32; s; s >>= 1) acc += __shfl_down(acc, s, 64);
    if (lane == 0) out[(size_t)row * 14 + off + o] = acc + b2[o];
}

// ---------------------------------------------------------------------------
extern "C" void kernel_launch(void* const* d_in, const int* in_sizes, int n_in,
                              void* d_out, int out_size, void* d_ws, size_t ws_size,
                              hipStream_t stream)
{
    const float* x_edge   = (const float*)d_in[1];
    const float* et_w     = (const float*)d_in[6];
    const float* et_b     = (const float*)d_in[7];
    const float* egru_wih = (const float*)d_in[11];
    const float* egru_bih = (const float*)d_in[12];
    const float* egru_bhh = (const float*)d_in[13];
    const float* natt_w   = (const float*)d_in[14];
    const float* eatt_w   = (const float*)d_in[16];
    const float* lr_w1 = (const float*)d_in[18];
    const float* lr_b1 = (const float*)d_in[19];
    const float* lr_w2 = (const float*)d_in[20];
    const float* lr_b2 = (const float*)d_in[21];
    const float* cr_w1 = (const float*)d_in[22];
    const float* cr_b1 = (const float*)d_in[23];
    const float* cr_w2 = (const float*)d_in[24];
    const float* cr_b2 = (const float*)d_in[25];
    const float* mr_w1 = (const float*)d_in[26];
    const float* mr_b1 = (const float*)d_in[27];
    const float* mr_w2 = (const float*)d_in[28];
    const float* mr_b2 = (const float*)d_in[29];
    const int* pairs   = (const int*)d_in[30];
    float* out = (float*)d_out;
    float* ws  = (float*)d_ws;

    const int Mtot = 16 * 64 * 64;          // 65536 edge rows

    // fixed ws: nh_p [1024,128], u [1024], ci [2048,256], hbuf [2048,512]
    const size_t NHP_F = 1024 * 128;
    const size_t U_F   = 1024;
    const size_t CI_F  = 2048 * 256;
    const size_t HB_F  = 2048 * 512;
    const size_t fixed_f = NHP_F + U_F + CI_F + HB_F;

    int CH = 1;
    while (CH < 64) {
        size_t need = (fixed_f + (size_t)(Mtot / CH) * 512) * sizeof(float);
        if (need <= ws_size) break;
        CH *= 2;
    }
    const int Mc = Mtot / CH;               // edge rows per chunk (mult of 64)
    const int groups_per_chunk = Mc / 64;   // (b,i) groups per chunk

    float* nh_p = ws;
    float* u    = nh_p + NHP_F;
    float* ci   = u + U_F;
    float* hbuf = ci + CI_F;                    // [2048,512]
    float* g_c  = hbuf + HB_F;                  // [Mc,384]
    float* ef_c = g_c + (size_t)Mc * 384;       // [Mc,128], reused as eh_c

    for (int c = 0; c < CH; ++c) {
        const float* A = x_edge + (size_t)c * Mc * 512;
        // edge_f = x_edge @ et_w + et_b
        gemm_f32<false, false><<<dim3(Mc / 64, 128 / 64), 256, 0, stream>>>(
            A, et_w, et_b, ef_c, Mc, 128, 512);
        // g = edge_f @ egru_wih^T + egru_bih
        gemm_f32<true, false><<<dim3(Mc / 64, 384 / 64), 256, 0, stream>>>(
            ef_c, egru_wih, egru_bih, g_c, Mc, 384, 128);
        // GRU gates -> eh (overwrite ef_c)
        gru_gates<<<(Mc * 128) / 256, 256, 0, stream>>>(g_c, egru_bhh, ef_c, Mc);
        // softmax-pool over j -> nh_p, u
        pool_kernel<<<groups_per_chunk, 256, 0, stream>>>(
            ef_c, natt_w, eatt_w, nh_p, u, c * groups_per_chunk);
    }

    ci_kernel<<<2048, 128, 0, stream>>>(nh_p, u, pairs, ci);

    // --- classifier heads: layer1 as tiled GEMM, layer2 wave-per-output ---
    const float* W1[3] = {lr_w1, cr_w1, mr_w1};
    const float* B1[3] = {lr_b1, cr_b1, mr_b1};
    const float* W2[3] = {lr_w2, cr_w2, mr_w2};
    const float* B2[3] = {lr_b2, cr_b2, mr_b2};
    const int OD[3]  = {6, 5, 3};
    const int OFF[3] = {0, 6, 11};
    for (int h = 0; h < 3; ++h) {
        gemm_f32<false, true><<<dim3(2048 / 64, 512 / 64), 256, 0, stream>>>(
            ci, W1[h], B1[h], hbuf, 2048, 512, 256);
        int nidx = 2048 * OD[h];
        layer2_kernel<<<(nidx + 3) / 4, 256, 0, stream>>>(
            hbuf, W2[h], B2[h], out, OD[h], OFF[h]);
    }
}

// Round 3
// 182.588 us; speedup vs baseline: 4.8327x; 2.1727x over previous
//
#include <hip/hip_runtime.h>
#include <math.h>
#include <stdint.h>

// ---------------------------------------------------------------------------
// Algebraic reductions (verified in rounds 1-2, absmax 0.0):
//  * 2-step loop idempotent -> run once; node branch cancels entirely.
//  * NEW: edge_f only feeds the GRU -> compose the two GEMMs:
//      g = x_edge @ Wc + bc,  Wc = et_w @ egru_wih^T  [512,384],
//      bc = et_b @ egru_wih^T + egru_bih (+ egru_bhh folded for r,z gates).
//  * GRU gates + softmax-pool fused into GEMM epilogue (64-row block = one
//    (b,i) group); eh never materialized in HBM.
//  * Precision: split-bf16 (hi+lo) 3-term MFMA == ~f32 accuracy.
// Output: [16,128,14] f32
// ---------------------------------------------------------------------------

typedef __attribute__((ext_vector_type(8))) short short8;
typedef __attribute__((ext_vector_type(4))) float f32x4;

#define DEVINL __device__ __forceinline__

DEVINL float sigmoidf_(float x) { return 1.0f / (1.0f + __expf(-x)); }
DEVINL float tanhf_(float x) {
    float e = __expf(2.0f * x);
    return (e - 1.0f) / (e + 1.0f);
}
DEVINL short bf16_rne(float f) {
    uint32_t u = __float_as_uint(f);
    u += 0x7FFFu + ((u >> 16) & 1u);
    return (short)(u >> 16);
}
DEVINL float bf16_to_f(short s) {
    return __uint_as_float(((uint32_t)(uint16_t)s) << 16);
}
DEVINL void gload_lds16(const void* g, void* l) {
    __builtin_amdgcn_global_load_lds(
        (const __attribute__((address_space(1))) void*)(uintptr_t)g,
        (__attribute__((address_space(3))) void*)(uint32_t)(uintptr_t)l,
        16, 0, 0);
}

// ---------------- prep: Wc in MFMA fragment order, split hi/lo -------------
// Wc[k][n] = sum_m et_w[k][m] * egru_wih[n][m];  k<512, n<384.
// Fragment order: [kt(16)][ct(24)][lane(64)][j(8)],
//   k = kt*32 + ((lane>>4)&3)*8 + j,  n = ct*16 + (lane&15).
__global__ __launch_bounds__(256) void prep_w(
    const float* __restrict__ et_w, const float* __restrict__ wih,
    short* __restrict__ Wf_hi, short* __restrict__ Wf_lo)
{
    int idx = blockIdx.x * 256 + threadIdx.x;   // idx = n*512 + k
    int n = idx >> 9, k = idx & 511;
    const float4* a = (const float4*)(et_w + (size_t)k * 128);
    const float4* b = (const float4*)(wih + (size_t)n * 128);
    float acc = 0.f;
#pragma unroll 8
    for (int m = 0; m < 32; ++m) {
        float4 x = a[m], y = b[m];
        acc += x.x * y.x + x.y * y.y + x.z * y.z + x.w * y.w;
    }
    short h = bf16_rne(acc);
    short l = bf16_rne(acc - bf16_to_f(h));
    int kt = k >> 5, ct = n >> 4;
    int lane = (((k >> 3) & 3) << 4) | (n & 15);
    int j = k & 7;
    size_t fidx = ((((size_t)kt * 24 + ct) * 64) + lane) * 8 + j;
    Wf_hi[fidx] = h;
    Wf_lo[fidx] = l;
}

// bc[n] = et_b . egru_wih[n] + egru_bih[n] (+ egru_bhh[n] for n<256)
__global__ __launch_bounds__(256) void prep_b(
    const float* __restrict__ et_b, const float* __restrict__ wih,
    const float* __restrict__ bih, const float* __restrict__ bhh,
    float* __restrict__ bc)
{
    int n = blockIdx.x * 256 + threadIdx.x;
    if (n >= 384) return;
    float acc = bih[n] + (n < 256 ? bhh[n] : 0.f);
    const float* w = wih + (size_t)n * 128;
    for (int m = 0; m < 128; ++m) acc = fmaf(et_b[m], w[m], acc);
    bc[n] = acc;
}

// ---------------- mega: GEMM + GRU gates + softmax-pool --------------------
// One block per (b,i) group: 64 rows (j) x 384 cols, K=512.
// 4 waves; wave wv owns gate-triple cols o in [wv*32, wv*32+32).
__global__ __launch_bounds__(256, 2) void mega_kernel(
    const float* __restrict__ x_edge,
    const short* __restrict__ Wf_hi, const short* __restrict__ Wf_lo,
    const float* __restrict__ bc, const float* __restrict__ bhh,
    const float* __restrict__ natt_w, const float* __restrict__ eatt_w,
    float* __restrict__ nh_p, float* __restrict__ u_out)
{
    __shared__ __align__(16) char smem[57344];
    short* Bs_hi = (short*)smem;               // 12288 shorts (24 KB)
    short* Bs_lo = Bs_hi + 12288;              // 24 KB
    short* As_hi = Bs_lo + 12288;              // 2048 shorts (4 KB)
    short* As_lo = As_hi + 2048;               // 4 KB

    const int t = threadIdx.x;
    const int wv = t >> 6, lane = t & 63;
    const int g = blockIdx.x;
    const size_t bm = (size_t)g * 64;

    // A staging assignment: thread -> (row, k-block of 8)
    const int arow = t >> 2, akb = t & 3;
    const int aslot = (((arow >> 4) * 64) + ((akb << 4) | (arow & 15))) * 8;
    const float* aptr = x_edge + (bm + arow) * 512 + akb * 8;

    f32x4 acc[4][6] = {};

    float4 a0 = *(const float4*)(aptr);
    float4 a1 = *(const float4*)(aptr + 4);

    for (int kt = 0; kt < 16; ++kt) {
        if (kt) __syncthreads();
        // B: async global->LDS (fragment order is linear copy)
        {
            const char* src_h = (const char*)(Wf_hi + (size_t)kt * 12288);
            const char* src_l = (const char*)(Wf_lo + (size_t)kt * 12288);
#pragma unroll
            for (int i = 0; i < 6; ++i) {
                int chunk = i * 4 + wv;
                int off = chunk * 1024 + lane * 16;
                gload_lds16(src_h + off, (char*)Bs_hi + chunk * 1024);
                gload_lds16(src_l + off, (char*)Bs_lo + chunk * 1024);
            }
        }
        // A: f32 -> hi/lo bf16, ds_write in fragment order
        {
            float av[8] = {a0.x, a0.y, a0.z, a0.w, a1.x, a1.y, a1.z, a1.w};
            short8 h8, l8;
#pragma unroll
            for (int j = 0; j < 8; ++j) {
                short h = bf16_rne(av[j]);
                h8[j] = h;
                l8[j] = bf16_rne(av[j] - bf16_to_f(h));
            }
            *(short8*)(As_hi + aslot) = h8;
            *(short8*)(As_lo + aslot) = l8;
        }
        if (kt < 15) {   // prefetch next A tile
            a0 = *(const float4*)(aptr + (kt + 1) * 32);
            a1 = *(const float4*)(aptr + (kt + 1) * 32 + 4);
        }
        __syncthreads();
        // compute: 4 row-tiles x 6 col-tiles x 3 split terms
        short8 Ah[4], Al[4];
#pragma unroll
        for (int rt = 0; rt < 4; ++rt) {
            Ah[rt] = *(const short8*)(As_hi + (rt * 64 + lane) * 8);
            Al[rt] = *(const short8*)(As_lo + (rt * 64 + lane) * 8);
        }
#pragma unroll
        for (int c = 0; c < 6; ++c) {
            int ctg = ((c >> 1) << 3) + (wv << 1) + (c & 1);
            short8 Bh = *(const short8*)(Bs_hi + (ctg * 64 + lane) * 8);
            short8 Bl = *(const short8*)(Bs_lo + (ctg * 64 + lane) * 8);
#pragma unroll
            for (int rt = 0; rt < 4; ++rt) {
                acc[rt][c] = __builtin_amdgcn_mfma_f32_16x16x32_bf16(Ah[rt], Bh, acc[rt][c], 0, 0, 0);
                acc[rt][c] = __builtin_amdgcn_mfma_f32_16x16x32_bf16(Al[rt], Bh, acc[rt][c], 0, 0, 0);
                acc[rt][c] = __builtin_amdgcn_mfma_f32_16x16x32_bf16(Ah[rt], Bl, acc[rt][c], 0, 0, 0);
            }
        }
    }
    __syncthreads();

    // ---- epilogue: GRU gates -> eh_s (overlay LDS) ----
    const int EHP = 132;                        // padded stride (bank spread)
    float* eh_s = (float*)smem;                 // [64][132] f32 = 33792 B
#pragma unroll
    for (int cc = 0; cc < 2; ++cc) {
        int o = (wv << 5) + (cc << 4) + (lane & 15);
        float bco = bc[o], bcz = bc[128 + o], bcn = bc[256 + o], bn3 = bhh[256 + o];
#pragma unroll
        for (int rt = 0; rt < 4; ++rt) {
#pragma unroll
            for (int q = 0; q < 4; ++q) {
                int row = rt * 16 + ((lane >> 4) << 2) + q;
                float r = sigmoidf_(acc[rt][cc][q] + bco);
                float z = sigmoidf_(acc[rt][2 + cc][q] + bcz);
                float n = tanhf_(acc[rt][4 + cc][q] + bcn + r * bn3);
                eh_s[row * EHP + o] = (1.0f - z) * n;
            }
        }
    }
    __syncthreads();

    // ---- softmax-pool over j (64 rows) ----
    float* red = eh_s + 64 * EHP;   // 256 f
    float* s2v = red + 256;         // 64 f
    float* ewv = s2v + 64;          // 64 f
    {
        int j = t >> 2, q = t & 3;
        const float* row = eh_s + j * EHP + q * 32;
        const float* wb = natt_w + 128 + q * 32;
        float a = 0.f;
#pragma unroll
        for (int k2 = 0; k2 < 32; ++k2) a = fmaf(row[k2], wb[k2], a);
        red[t] = a;
    }
    __syncthreads();
    if (t < 64) s2v[t] = red[4 * t] + red[4 * t + 1] + red[4 * t + 2] + red[4 * t + 3];
    __syncthreads();
    if (t < 64) {
        float m = -1e30f;
        for (int j = 0; j < 64; ++j) m = fmaxf(m, s2v[j]);
        ewv[t] = __expf(s2v[t] - m);
    }
    __syncthreads();
    float inv = 0.f;
    for (int j = 0; j < 64; ++j) inv += ewv[j];
    inv = 1.0f / inv;
    {
        int o = t & 127, h = t >> 7;
        float a = 0.f;
        for (int j = h * 32; j < h * 32 + 32; ++j)
            a = fmaf(ewv[j], eh_s[j * EHP + o], a);
        __syncthreads();
        red[t] = a;
    }
    __syncthreads();
    if (t < 128) {
        float v = (red[t] + red[t + 128]) * inv;
        nh_p[(size_t)g * 128 + t] = v;
        red[t] = v * eatt_w[t];
    }
    __syncthreads();
    for (int s = 64; s > 0; s >>= 1) {
        if (t < s) red[t] += red[t + s];
        __syncthreads();
    }
    if (t == 0) u_out[g] = red[0];
}

// ---------------- tiled f32 GEMM (heads layer 1) ---------------------------
template <bool BT, bool RELU>
__global__ __launch_bounds__(256) void gemm_f32(
    const float* __restrict__ A, const float* __restrict__ B,
    const float* __restrict__ bias, float* __restrict__ C,
    int M, int N, int K)
{
    __shared__ float As[16][64];
    __shared__ float Bs[16][64];
    const int t  = threadIdx.x;
    const int bm = blockIdx.x * 64;
    const int bn = blockIdx.y * 64;
    const int tr = t >> 4, tc = t & 15;
    float acc[4][4] = {};
    for (int kt = 0; kt < K; kt += 16) {
#pragma unroll
        for (int l = 0; l < 4; ++l) {
            int e = t + l * 256;
            int m = e >> 4, k = e & 15;
            As[k][m] = A[(size_t)(bm + m) * K + kt + k];
        }
#pragma unroll
        for (int l = 0; l < 4; ++l) {
            int e = t + l * 256;
            if (!BT) {
                int k = e >> 6, n = e & 63;
                Bs[k][n] = B[(size_t)(kt + k) * N + bn + n];
            } else {
                int n = e >> 4, k = e & 15;
                Bs[k][n] = B[(size_t)(bn + n) * K + kt + k];
            }
        }
        __syncthreads();
#pragma unroll
        for (int k = 0; k < 16; ++k) {
            const float4 a4 = *(const float4*)(&As[k][tr * 4]);
            const float4 b4 = *(const float4*)(&Bs[k][tc * 4]);
            const float av[4] = {a4.x, a4.y, a4.z, a4.w};
            const float bv[4] = {b4.x, b4.y, b4.z, b4.w};
#pragma unroll
            for (int i = 0; i < 4; ++i)
#pragma unroll
                for (int j = 0; j < 4; ++j)
                    acc[i][j] = fmaf(av[i], bv[j], acc[i][j]);
        }
        __syncthreads();
    }
    const float4 bb = *(const float4*)(&bias[bn + tc * 4]);
    const float bv[4] = {bb.x, bb.y, bb.z, bb.w};
#pragma unroll
    for (int i = 0; i < 4; ++i) {
        int row = bm + tr * 4 + i;
        float4 v;
        float o0 = acc[i][0] + bv[0];
        float o1 = acc[i][1] + bv[1];
        float o2 = acc[i][2] + bv[2];
        float o3 = acc[i][3] + bv[3];
        if (RELU) {
            o0 = fmaxf(o0, 0.f); o1 = fmaxf(o1, 0.f);
            o2 = fmaxf(o2, 0.f); o3 = fmaxf(o3, 0.f);
        }
        v.x = o0; v.y = o1; v.z = o2; v.w = o3;
        *(float4*)(&C[(size_t)row * N + bn + tc * 4]) = v;
    }
}

// -------- classifier input --------------------------------------------------
__global__ __launch_bounds__(128) void ci_kernel(
    const float* __restrict__ nh_p, const float* __restrict__ u,
    const int* __restrict__ pairs, float* __restrict__ ci)
{
    const int bp = blockIdx.x;
    const int b  = bp >> 7;
    const int t  = threadIdx.x;
    int i0 = pairs[bp * 2 + 0];
    int i1 = pairs[bp * 2 + 1];
    const float* n0 = nh_p + (size_t)(b * 64 + i0) * 128;
    const float* n1 = nh_p + (size_t)(b * 64 + i1) * 128;
    float s = sigmoidf_(u[b * 64 + i1] - u[b * 64 + i0]);
    float v0 = n0[t], v1 = n1[t];
    ci[(size_t)bp * 256 + t]       = 0.5f * (v0 + v1);
    ci[(size_t)bp * 256 + 128 + t] = s * v1 + (1.0f - s) * v0;
}

// -------- head layer 2: one wave per (row, o) -------------------------------
__global__ __launch_bounds__(256) void layer2_kernel(
    const float* __restrict__ h, const float* __restrict__ w2,
    const float* __restrict__ b2, float* __restrict__ out, int od, int off)
{
    const int wv   = threadIdx.x >> 6;
    const int lane = threadIdx.x & 63;
    const int idx  = blockIdx.x * 4 + wv;
    if (idx >= 2048 * od) return;
    const int row = idx / od;
    const int o   = idx - row * od;
    const float* hr = h + (size_t)row * 512;
    float acc = 0.f;
#pragma unroll
    for (int c = lane; c < 512; c += 64)
        acc = fmaf(hr[c], w2[(size_t)c * od + o], acc);
#pragma unroll
    for (int s = 32; s; s >>= 1) acc += __shfl_down(acc, s, 64);
    if (lane == 0) out[(size_t)row * 14 + off + o] = acc + b2[o];
}

// ---------------------------------------------------------------------------
extern "C" void kernel_launch(void* const* d_in, const int* in_sizes, int n_in,
                              void* d_out, int out_size, void* d_ws, size_t ws_size,
                              hipStream_t stream)
{
    const float* x_edge   = (const float*)d_in[1];
    const float* et_w     = (const float*)d_in[6];
    const float* et_b     = (const float*)d_in[7];
    const float* egru_wih = (const float*)d_in[11];
    const float* egru_bih = (const float*)d_in[12];
    const float* egru_bhh = (const float*)d_in[13];
    const float* natt_w   = (const float*)d_in[14];
    const float* eatt_w   = (const float*)d_in[16];
    const float* lr_w1 = (const float*)d_in[18];
    const float* lr_b1 = (const float*)d_in[19];
    const float* lr_w2 = (const float*)d_in[20];
    const float* lr_b2 = (const float*)d_in[21];
    const float* cr_w1 = (const float*)d_in[22];
    const float* cr_b1 = (const float*)d_in[23];
    const float* cr_w2 = (const float*)d_in[24];
    const float* cr_b2 = (const float*)d_in[25];
    const float* mr_w1 = (const float*)d_in[26];
    const float* mr_b1 = (const float*)d_in[27];
    const float* mr_w2 = (const float*)d_in[28];
    const float* mr_b2 = (const float*)d_in[29];
    const int* pairs   = (const int*)d_in[30];
    float* out = (float*)d_out;
    char* ws = (char*)d_ws;

    // workspace layout (bytes)
    short* Wf_hi = (short*)(ws);                         // 393216 B
    short* Wf_lo = (short*)(ws + 393216);                // 393216 B
    float* bc    = (float*)(ws + 786432);                // 1536 B
    float* nh_p  = (float*)(ws + 787968);                // 524288 B
    float* u     = (float*)(ws + 1312256);               // 4096 B
    float* ci    = (float*)(ws + 1316352);               // 2097152 B
    float* hbuf  = (float*)(ws + 3413504);               // 4194304 B

    prep_w<<<768, 256, 0, stream>>>(et_w, egru_wih, Wf_hi, Wf_lo);
    prep_b<<<2, 256, 0, stream>>>(et_b, egru_wih, egru_bih, egru_bhh, bc);

    mega_kernel<<<1024, 256, 0, stream>>>(
        x_edge, Wf_hi, Wf_lo, bc, egru_bhh, natt_w, eatt_w, nh_p, u);

    ci_kernel<<<2048, 128, 0, stream>>>(nh_p, u, pairs, ci);

    const float* W1[3] = {lr_w1, cr_w1, mr_w1};
    const float* B1[3] = {lr_b1, cr_b1, mr_b1};
    const float* W2[3] = {lr_w2, cr_w2, mr_w2};
    const float* B2[3] = {lr_b2, cr_b2, mr_b2};
    const int OD[3]  = {6, 5, 3};
    const int OFF[3] = {0, 6, 11};
    for (int h = 0; h < 3; ++h) {
        gemm_f32<false, true><<<dim3(2048 / 64, 512 / 64), 256, 0, stream>>>(
            ci, W1[h], B1[h], hbuf, 2048, 512, 256);
        int nidx = 2048 * OD[h];
        layer2_kernel<<<(nidx + 3) / 4, 256, 0, stream>>>(
            hbuf, W2[h], B2[h], out, OD[h], OFF[h]);
    }
}